// Round 1
// baseline (383.415 us; speedup 1.0000x reference)
//
#include <hip/hip_runtime.h>
#include <math.h>

// TripletLoss: N=8192 embeddings, D=128, labels in [0,512).
// loss = mean over valid rows of max(hardest_pos - hardest_neg + 0.3, 1e-6)
// Strategy: fused tiled pairwise-distance kernel, never materialize NxN.
//   prep:     sq[i] = ||x_i||^2, label histogram, init hp=0 / hn=+inf
//   pair:     64x64 register-tiled dot products; per-row max/min with
//             bitcast uint atomics across a 4-way column split
//   finalize: single-block reduction to the scalar
// Validity: row i valid  <=>  hist[label[i]] >= 2  &&  hist[label[i]] < N
// (positives exist besides self; at least one different label exists).

#define NROWS 8192
#define DIM   128
#define BM    64
#define BN    64
#define COLSPLIT 4
#define COLS_PER (NROWS / COLSPLIT)
#define LDK   (DIM + 4)   // pad 4 floats: keeps float4 alignment, breaks pow2 stride

__global__ __launch_bounds__(256) void prep_kernel(
    const float* __restrict__ x, const int* __restrict__ labels,
    float* __restrict__ sq, unsigned* __restrict__ hp_g,
    unsigned* __restrict__ hn_g, int* __restrict__ hist) {
    int i = blockIdx.x * 256 + threadIdx.x;
    if (i >= NROWS) return;
    const float4* xv = (const float4*)(x + (size_t)i * DIM);
    float s = 0.f;
#pragma unroll
    for (int k = 0; k < DIM / 4; ++k) {
        float4 v = xv[k];
        s += v.x * v.x + v.y * v.y + v.z * v.z + v.w * v.w;
    }
    sq[i] = s;
    hp_g[i] = 0u;           // distances >= 0, so uint-max from 0 is safe
    hn_g[i] = 0x7F800000u;  // +inf bits; uint-min correct for non-neg floats
    atomicAdd(&hist[labels[i]], 1);
}

__global__ __launch_bounds__(256, 2) void pair_kernel(
    const float* __restrict__ x, const int* __restrict__ labels,
    const float* __restrict__ sq, unsigned* __restrict__ hp_g,
    unsigned* __restrict__ hn_g) {
    __shared__ float As[BM][LDK];
    __shared__ float Bs[BN][LDK];
    __shared__ int   labB[BN];
    __shared__ float sqB[BN];

    const int tid = threadIdx.x;
    const int tx = tid & 15;
    const int ty = tid >> 4;
    const int rowBase = blockIdx.x * BM;
    const int colBase0 = blockIdx.y * COLS_PER;

    // Load A tile once (rows fixed for this block): 64x128 floats = 2048 float4
#pragma unroll
    for (int u = 0; u < (BM * DIM / 4) / 256; ++u) {
        int f = tid + u * 256;
        int r = f >> 5;        // 32 float4 per row
        int k4 = f & 31;
        float4 v = ((const float4*)x)[(size_t)(rowBase + r) * (DIM / 4) + k4];
        *(float4*)&As[r][k4 * 4] = v;
    }

    int   rlab[4];
    float rsq[4];
#pragma unroll
    for (int i = 0; i < 4; ++i) {
        int r = rowBase + ty + 16 * i;
        rlab[i] = labels[r];
        rsq[i] = sq[r];
    }

    float hp[4] = {0.f, 0.f, 0.f, 0.f};
    float hn[4];
#pragma unroll
    for (int i = 0; i < 4; ++i) hn[i] = __uint_as_float(0x7F800000u);

    for (int ct = 0; ct < COLS_PER / BN; ++ct) {
        int colBase = colBase0 + ct * BN;
        __syncthreads();  // previous iteration's Bs reads done
#pragma unroll
        for (int u = 0; u < (BN * DIM / 4) / 256; ++u) {
            int f = tid + u * 256;
            int c = f >> 5;
            int k4 = f & 31;
            float4 v = ((const float4*)x)[(size_t)(colBase + c) * (DIM / 4) + k4];
            *(float4*)&Bs[c][k4 * 4] = v;
        }
        if (tid < BN) {
            labB[tid] = labels[colBase + tid];
            sqB[tid] = sq[colBase + tid];
        }
        __syncthreads();

        float acc[4][4];
#pragma unroll
        for (int i = 0; i < 4; ++i)
#pragma unroll
            for (int j = 0; j < 4; ++j) acc[i][j] = 0.f;

#pragma unroll 8
        for (int k = 0; k < DIM; ++k) {
            float a[4], b[4];
#pragma unroll
            for (int i = 0; i < 4; ++i) a[i] = As[ty + 16 * i][k];
#pragma unroll
            for (int j = 0; j < 4; ++j) b[j] = Bs[tx + 16 * j][k];
#pragma unroll
            for (int i = 0; i < 4; ++i)
#pragma unroll
                for (int j = 0; j < 4; ++j) acc[i][j] = fmaf(a[i], b[j], acc[i][j]);
        }

        // Distance + hardest pos/neg update for this 64-col tile
#pragma unroll
        for (int j = 0; j < 4; ++j) {
            int ccol = colBase + tx + 16 * j;
            int cl = labB[tx + 16 * j];
            float csq = sqB[tx + 16 * j];
#pragma unroll
            for (int i = 0; i < 4; ++i) {
                int r = rowBase + ty + 16 * i;
                float d2 = rsq[i] + csq - 2.f * acc[i][j];
                float d = sqrtf(fmaxf(d2, 1e-12f));
                if (rlab[i] == cl) {
                    if (ccol != r) hp[i] = fmaxf(hp[i], d);
                } else {
                    hn[i] = fminf(hn[i], d);
                }
            }
        }
    }

    // Reduce across the 16 tx lanes (lane bits 0..3) sharing each row
#pragma unroll
    for (int i = 0; i < 4; ++i) {
#pragma unroll
        for (int s = 1; s < 16; s <<= 1) {
            hp[i] = fmaxf(hp[i], __shfl_xor(hp[i], s, 64));
            hn[i] = fminf(hn[i], __shfl_xor(hn[i], s, 64));
        }
    }
    if (tx == 0) {
#pragma unroll
        for (int i = 0; i < 4; ++i) {
            int r = rowBase + ty + 16 * i;
            atomicMax(&hp_g[r], __float_as_uint(hp[i]));
            atomicMin(&hn_g[r], __float_as_uint(hn[i]));
        }
    }
}

__global__ __launch_bounds__(256) void finalize_kernel(
    const unsigned* __restrict__ hp_g, const unsigned* __restrict__ hn_g,
    const int* __restrict__ labels, const int* __restrict__ hist,
    float* __restrict__ out) {
    int tid = threadIdx.x;
    float sum = 0.f;
    float cnt = 0.f;
    for (int r = tid; r < NROWS; r += 256) {
        int h = hist[labels[r]];
        if (h >= 2 && h < NROWS) {
            float hp = __uint_as_float(hp_g[r]);
            float hn = __uint_as_float(hn_g[r]);
            sum += fmaxf(hp - hn + 0.3f, 1e-6f);
            cnt += 1.f;
        }
    }
    __shared__ float ssum[256];
    __shared__ float scnt[256];
    ssum[tid] = sum;
    scnt[tid] = cnt;
    __syncthreads();
    for (int s = 128; s > 0; s >>= 1) {
        if (tid < s) {
            ssum[tid] += ssum[tid + s];
            scnt[tid] += scnt[tid + s];
        }
        __syncthreads();
    }
    if (tid == 0) out[0] = (scnt[0] > 0.f) ? (ssum[0] / scnt[0]) : 0.f;
}

extern "C" void kernel_launch(void* const* d_in, const int* in_sizes, int n_in,
                              void* d_out, int out_size, void* d_ws, size_t ws_size,
                              hipStream_t stream) {
    const float* x = (const float*)d_in[0];
    const int* labels = (const int*)d_in[1];
    float* out = (float*)d_out;

    // Workspace layout (all within first ~104 KB of d_ws):
    //   [0, 2048)      int hist[512]            (memset to 0 below)
    //   [4096, ...)    float sq[8192]
    //   then           unsigned hp[8192], unsigned hn[8192]
    char* ws = (char*)d_ws;
    int* hist = (int*)ws;
    float* sq = (float*)(ws + 4096);
    unsigned* hp = (unsigned*)(ws + 4096 + NROWS * 4);
    unsigned* hn = (unsigned*)(ws + 4096 + 2 * NROWS * 4);

    hipMemsetAsync(hist, 0, 4096, stream);
    prep_kernel<<<NROWS / 256, 256, 0, stream>>>(x, labels, sq, hp, hn, hist);
    pair_kernel<<<dim3(NROWS / BM, COLSPLIT), 256, 0, stream>>>(x, labels, sq, hp, hn);
    finalize_kernel<<<1, 256, 0, stream>>>(hp, hn, labels, hist, out);
}

// Round 2
// 132.143 us; speedup vs baseline: 2.9015x; 2.9015x over previous
//
#include <hip/hip_runtime.h>
#include <math.h>

// TripletLoss N=8192, D=128, labels in [0,512). Round 2: bf16 MFMA Gram.
//   prep:  sq[i]=||x_i||^2 (fp32), xb=bf16(x) [B/i operand], xm2=bf16(-2x)
//          [A/j operand], label hist, init hp(d^2)=0 / hn(d^2)=+inf bits.
//   pair:  per wave: 64 i x JCHUNK j. MFMA 16x16x32 bf16, C init = sq_j
//          (fp32, exact) so acc = sq_j - 2*dot. Track max/min of t over j
//          (sq_i folded after reduction; sqrt deferred to finalize —
//          monotone). Self-pair gives d^2 ~ +-0.1 << real positives: no
//          self check needed. A-frags read straight from global (L2-resident
//          2 MB) — no LDS, no barriers.
//   finalize: loss = mean over valid rows of max(sqrt(hp)-sqrt(hn)+0.3,1e-6)
// Validity: hist[lab] >= 2 && hist[lab] < N  (matches reference mask).

#define NROWS 8192
#define DIM   128
#define JSPLIT 32
#define JCHUNK (NROWS / JSPLIT)   // 256 j per block

typedef short bf16x8 __attribute__((ext_vector_type(8)));
typedef float f32x4  __attribute__((ext_vector_type(4)));

static __device__ __forceinline__ unsigned short f2bf(float f) {
    unsigned u = __float_as_uint(f);
    unsigned r = (u + 0x7FFFu + ((u >> 16) & 1u)) >> 16;   // RNE
    return (unsigned short)r;
}

// one thread per float4 chunk: 8192*32 = 262144 threads
__global__ __launch_bounds__(256) void prep_kernel(
    const float* __restrict__ x, const int* __restrict__ labels,
    float* __restrict__ sq, unsigned* __restrict__ hp_g,
    unsigned* __restrict__ hn_g, int* __restrict__ hist,
    unsigned short* __restrict__ xb, unsigned short* __restrict__ xm2) {
    int t = blockIdx.x * 256 + threadIdx.x;      // 0..262143
    int row = t >> 5;                            // 32 float4 per row
    int c = t & 31;
    float4 v = ((const float4*)x)[t];
    float ps = v.x * v.x + v.y * v.y + v.z * v.z + v.w * v.w;
#pragma unroll
    for (int s = 1; s < 32; s <<= 1) ps += __shfl_xor(ps, s, 64);
    if (c == 0) {
        sq[row] = ps;
        hp_g[row] = 0u;            // d^2 domain, >= 0
        hn_g[row] = 0x7F800000u;   // +inf bits
        atomicAdd(&hist[labels[row]], 1);
    }
    ushort4 ob, om;
    ob.x = f2bf(v.x); ob.y = f2bf(v.y); ob.z = f2bf(v.z); ob.w = f2bf(v.w);
    om.x = f2bf(-2.f * v.x); om.y = f2bf(-2.f * v.y);
    om.z = f2bf(-2.f * v.z); om.w = f2bf(-2.f * v.w);
    ((ushort4*)xb)[t] = ob;
    ((ushort4*)xm2)[t] = om;
}

__global__ __launch_bounds__(256) void pair_kernel(
    const unsigned short* __restrict__ xb,   // bf16(x), i/B side
    const unsigned short* __restrict__ xm2,  // bf16(-2x), j/A side
    const float* __restrict__ sq, const int* __restrict__ labels,
    unsigned* __restrict__ hp_g, unsigned* __restrict__ hn_g) {
    const int lane = threadIdx.x & 63;
    const int wid = threadIdx.x >> 6;        // 0..3
    const int q = lane >> 4;                 // 0..3
    const int r = lane & 15;
    const int ibase = blockIdx.x * 256 + wid * 64;
    const int jbase = blockIdx.y * JCHUNK;

    // B-frags (i side), fixed for the whole j loop.
    // B[n=lane&15][k=q*8 .. q*8+8), k-offset ks*32 per MFMA step.
    bf16x8 bfrag[4][4];
    int labi[4];
    float sqi[4];
#pragma unroll
    for (int sub = 0; sub < 4; ++sub) {
        int irow = ibase + sub * 16 + r;
        labi[sub] = labels[irow];
        sqi[sub] = sq[irow];
#pragma unroll
        for (int ks = 0; ks < 4; ++ks)
            bfrag[sub][ks] = *(const bf16x8*)(xb + (size_t)irow * DIM + ks * 32 + q * 8);
    }

    float hp[4] = {-INFINITY, -INFINITY, -INFINITY, -INFINITY};
    float hn[4] = {INFINITY, INFINITY, INFINITY, INFINITY};

    for (int jt = 0; jt < JCHUNK / 16; ++jt) {
        const int j16 = jbase + jt * 16;
        // acc init = sq_j for rows q*4..q*4+3 (fp32, exact); labels likewise.
        f32x4 sqj = *(const f32x4*)(sq + j16 + q * 4);
        int4 labj = *(const int4*)(labels + j16 + q * 4);
        // A-frags: A[m=lane&15=j][k=q*8+..], row j16+r.
        const unsigned short* ap = xm2 + (size_t)(j16 + r) * DIM + q * 8;
        bf16x8 af0 = *(const bf16x8*)(ap);
        bf16x8 af1 = *(const bf16x8*)(ap + 32);
        bf16x8 af2 = *(const bf16x8*)(ap + 64);
        bf16x8 af3 = *(const bf16x8*)(ap + 96);

#pragma unroll
        for (int sub = 0; sub < 4; ++sub) {
            f32x4 acc = sqj;
            acc = __builtin_amdgcn_mfma_f32_16x16x32_bf16(af0, bfrag[sub][0], acc, 0, 0, 0);
            acc = __builtin_amdgcn_mfma_f32_16x16x32_bf16(af1, bfrag[sub][1], acc, 0, 0, 0);
            acc = __builtin_amdgcn_mfma_f32_16x16x32_bf16(af2, bfrag[sub][2], acc, 0, 0, 0);
            acc = __builtin_amdgcn_mfma_f32_16x16x32_bf16(af3, bfrag[sub][3], acc, 0, 0, 0);
            // acc[reg] = sq_j - 2*dot(x_j, x_i) for j = j16 + q*4 + reg
            const int li = labi[sub];
            float t0 = acc[0], t1 = acc[1], t2 = acc[2], t3 = acc[3];
            hp[sub] = fmaxf(hp[sub], (labj.x == li) ? t0 : -INFINITY);
            hn[sub] = fminf(hn[sub], (labj.x == li) ? INFINITY : t0);
            hp[sub] = fmaxf(hp[sub], (labj.y == li) ? t1 : -INFINITY);
            hn[sub] = fminf(hn[sub], (labj.y == li) ? INFINITY : t1);
            hp[sub] = fmaxf(hp[sub], (labj.z == li) ? t2 : -INFINITY);
            hn[sub] = fminf(hn[sub], (labj.z == li) ? INFINITY : t2);
            hp[sub] = fmaxf(hp[sub], (labj.w == li) ? t3 : -INFINITY);
            hn[sub] = fminf(hn[sub], (labj.w == li) ? INFINITY : t3);
        }
    }

    // reduce across the 4 q-groups (lanes r, r+16, r+32, r+48)
#pragma unroll
    for (int sub = 0; sub < 4; ++sub) {
        hp[sub] = fmaxf(hp[sub], __shfl_xor(hp[sub], 16, 64));
        hp[sub] = fmaxf(hp[sub], __shfl_xor(hp[sub], 32, 64));
        hn[sub] = fminf(hn[sub], __shfl_xor(hn[sub], 16, 64));
        hn[sub] = fminf(hn[sub], __shfl_xor(hn[sub], 32, 64));
    }
    if (lane < 16) {
#pragma unroll
        for (int sub = 0; sub < 4; ++sub) {
            int irow = ibase + sub * 16 + lane;
            float d2p = fmaxf(hp[sub] + sqi[sub], 1e-12f);  // -inf if none: ->1e-12
            float d2n = fmaxf(hn[sub] + sqi[sub], 1e-12f);  // +inf stays +inf
            atomicMax(&hp_g[irow], __float_as_uint(d2p));
            atomicMin(&hn_g[irow], __float_as_uint(d2n));
        }
    }
}

__global__ __launch_bounds__(256) void finalize_kernel(
    const unsigned* __restrict__ hp_g, const unsigned* __restrict__ hn_g,
    const int* __restrict__ labels, const int* __restrict__ hist,
    float* __restrict__ out) {
    int tid = threadIdx.x;
    float sum = 0.f, cnt = 0.f;
    for (int i = tid; i < NROWS; i += 256) {
        int h = hist[labels[i]];
        if (h >= 2 && h < NROWS) {
            float hp = sqrtf(__uint_as_float(hp_g[i]));
            float hn = sqrtf(__uint_as_float(hn_g[i]));
            sum += fmaxf(hp - hn + 0.3f, 1e-6f);
            cnt += 1.f;
        }
    }
    __shared__ float ssum[256], scnt[256];
    ssum[tid] = sum; scnt[tid] = cnt;
    __syncthreads();
    for (int s = 128; s > 0; s >>= 1) {
        if (tid < s) { ssum[tid] += ssum[tid + s]; scnt[tid] += scnt[tid + s]; }
        __syncthreads();
    }
    if (tid == 0) out[0] = (scnt[0] > 0.f) ? (ssum[0] / scnt[0]) : 0.f;
}

extern "C" void kernel_launch(void* const* d_in, const int* in_sizes, int n_in,
                              void* d_out, int out_size, void* d_ws, size_t ws_size,
                              hipStream_t stream) {
    const float* x = (const float*)d_in[0];
    const int* labels = (const int*)d_in[1];
    float* out = (float*)d_out;

    // ws layout (16B-aligned offsets):
    //   hist   @ 0        (4 KB)
    //   sq     @ 4096     (32 KB)
    //   hp     @ 36864    (32 KB)
    //   hn     @ 69632    (32 KB)
    //   xb     @ 102400   (2 MB bf16)
    //   xm2    @ 2199552  (2 MB bf16)   total ~4.3 MB
    char* ws = (char*)d_ws;
    int* hist = (int*)ws;
    float* sq = (float*)(ws + 4096);
    unsigned* hp = (unsigned*)(ws + 36864);
    unsigned* hn = (unsigned*)(ws + 69632);
    unsigned short* xb = (unsigned short*)(ws + 102400);
    unsigned short* xm2 = (unsigned short*)(ws + 2199552);

    hipMemsetAsync(hist, 0, 4096, stream);
    prep_kernel<<<(NROWS * 32) / 256, 256, 0, stream>>>(x, labels, sq, hp, hn, hist, xb, xm2);
    pair_kernel<<<dim3(NROWS / 256, JSPLIT), 256, 0, stream>>>(xb, xm2, sq, labels, hp, hn);
    finalize_kernel<<<1, 256, 0, stream>>>(hp, hn, labels, hist, out);
}

// Round 3
// 112.384 us; speedup vs baseline: 3.4116x; 1.1758x over previous
//
#include <hip/hip_runtime.h>
#include <math.h>

// TripletLoss N=8192, D=128, labels in [0,512). Round 3.
//   prep:   sq[i]=||x_i||^2 fp32 (wave shuffle), xb=bf16(x), label hist.
//   pair:   per wave 64i x 16j per iter, MFMA 16x16x32 bf16.
//           acc init = -0.5*sq_j  =>  u = dot(x_j,x_i) - 0.5*sq_j.
//           hardest_pos(d^2 max) == min u over positives;
//           hardest_neg(d^2 min) == max u over negatives  (d^2 = sq_i - 2u).
//           j-side loads explicitly double-buffered (ping-pong) so the
//           ~250cyc L2 latency hides under the previous tile's MFMA+epilogue.
//           Results written as per-(jsplit,row) partials — NO atomics.
//   reduce: 32 blocks; min/max over the 32 partials per row, validity via
//           hist, sqrt + margin, block-sum -> 2 atomicAdds.
//   final:  1 thread: out = sum/cnt.
// Self-pair never wins: u_self ~ +0.5*sq (largest u) while hp takes min u.
// Validity: hist[lab] >= 2 && hist[lab] < N (matches reference mask).

#define NROWS 8192
#define DIM   128
#define JSPLIT 32
#define JCHUNK (NROWS / JSPLIT)   // 256 j per y-block
#define NITER  (JCHUNK / 16)      // 16 j-tiles per block

typedef short bf16x8 __attribute__((ext_vector_type(8)));
typedef float f32x4  __attribute__((ext_vector_type(4)));

static __device__ __forceinline__ unsigned short f2bf(float f) {
    unsigned u = __float_as_uint(f);
    unsigned r = (u + 0x7FFFu + ((u >> 16) & 1u)) >> 16;   // RNE
    return (unsigned short)r;
}

// one thread per float4 chunk: 8192*32 = 262144 threads
__global__ __launch_bounds__(256) void prep_kernel(
    const float* __restrict__ x, const int* __restrict__ labels,
    float* __restrict__ sq, int* __restrict__ hist,
    unsigned short* __restrict__ xb) {
    int t = blockIdx.x * 256 + threadIdx.x;
    int row = t >> 5;
    int c = t & 31;
    float4 v = ((const float4*)x)[t];
    float ps = v.x * v.x + v.y * v.y + v.z * v.z + v.w * v.w;
#pragma unroll
    for (int s = 1; s < 32; s <<= 1) ps += __shfl_xor(ps, s, 64);
    if (c == 0) {
        sq[row] = ps;
        atomicAdd(&hist[labels[row]], 1);
    }
    ushort4 ob;
    ob.x = f2bf(v.x); ob.y = f2bf(v.y); ob.z = f2bf(v.z); ob.w = f2bf(v.w);
    ((ushort4*)xb)[t] = ob;
}

__global__ __launch_bounds__(256) void pair_kernel(
    const unsigned short* __restrict__ xb, const float* __restrict__ sq,
    const int* __restrict__ labels,
    float* __restrict__ hpp, float* __restrict__ hnp) {
    const int lane = threadIdx.x & 63;
    const int wid = threadIdx.x >> 6;        // 0..3
    const int q = lane >> 4;                 // 0..3
    const int r = lane & 15;
    const int ibase = blockIdx.x * 256 + wid * 64;
    const int jbase = blockIdx.y * JCHUNK;

    // B-frags (i side): B[n=r][k=ks*32 + q*8 ..], resident for whole j-loop.
    bf16x8 bfrag[4][4];
    int labi[4];
#pragma unroll
    for (int sub = 0; sub < 4; ++sub) {
        int irow = ibase + sub * 16 + r;
        labi[sub] = labels[irow];
#pragma unroll
        for (int ks = 0; ks < 4; ++ks)
            bfrag[sub][ks] = *(const bf16x8*)(xb + (size_t)irow * DIM + ks * 32 + q * 8);
    }

    float hp[4] = {INFINITY, INFINITY, INFINITY, INFINITY};     // min u (pos)
    float hn[4] = {-INFINITY, -INFINITY, -INFINITY, -INFINITY}; // max u (neg)

    auto loadA = [&](int j16, bf16x8 af[4], f32x4& sqj, int4& labj) {
        const unsigned short* ap = xb + (size_t)(j16 + r) * DIM + q * 8;
        af[0] = *(const bf16x8*)(ap);
        af[1] = *(const bf16x8*)(ap + 32);
        af[2] = *(const bf16x8*)(ap + 64);
        af[3] = *(const bf16x8*)(ap + 96);
        sqj = *(const f32x4*)(sq + j16 + q * 4);
        labj = *(const int4*)(labels + j16 + q * 4);
    };
    auto compute = [&](const bf16x8 af[4], const f32x4& sqj, const int4& labj) {
        f32x4 cinit;
        cinit[0] = -0.5f * sqj[0]; cinit[1] = -0.5f * sqj[1];
        cinit[2] = -0.5f * sqj[2]; cinit[3] = -0.5f * sqj[3];
#pragma unroll
        for (int sub = 0; sub < 4; ++sub) {
            f32x4 acc = cinit;
            acc = __builtin_amdgcn_mfma_f32_16x16x32_bf16(af[0], bfrag[sub][0], acc, 0, 0, 0);
            acc = __builtin_amdgcn_mfma_f32_16x16x32_bf16(af[1], bfrag[sub][1], acc, 0, 0, 0);
            acc = __builtin_amdgcn_mfma_f32_16x16x32_bf16(af[2], bfrag[sub][2], acc, 0, 0, 0);
            acc = __builtin_amdgcn_mfma_f32_16x16x32_bf16(af[3], bfrag[sub][3], acc, 0, 0, 0);
            const int li = labi[sub];
            float u0 = acc[0], u1 = acc[1], u2 = acc[2], u3 = acc[3];
            hp[sub] = fminf(hp[sub], (labj.x == li) ? u0 : INFINITY);
            hn[sub] = fmaxf(hn[sub], (labj.x == li) ? -INFINITY : u0);
            hp[sub] = fminf(hp[sub], (labj.y == li) ? u1 : INFINITY);
            hn[sub] = fmaxf(hn[sub], (labj.y == li) ? -INFINITY : u1);
            hp[sub] = fminf(hp[sub], (labj.z == li) ? u2 : INFINITY);
            hn[sub] = fmaxf(hn[sub], (labj.z == li) ? -INFINITY : u2);
            hp[sub] = fminf(hp[sub], (labj.w == li) ? u3 : INFINITY);
            hn[sub] = fmaxf(hn[sub], (labj.w == li) ? -INFINITY : u3);
        }
    };

    // Software-pipelined j-loop: ping-pong register buffers.
    bf16x8 afP[4], afQ[4];
    f32x4 sqjP, sqjQ;
    int4 labjP, labjQ;
    loadA(jbase, afP, sqjP, labjP);
#pragma unroll
    for (int jt = 0; jt < NITER; jt += 2) {
        loadA(jbase + (jt + 1) * 16, afQ, sqjQ, labjQ);
        compute(afP, sqjP, labjP);
        if (jt + 2 < NITER) loadA(jbase + (jt + 2) * 16, afP, sqjP, labjP);
        compute(afQ, sqjQ, labjQ);
    }

    // reduce across the 4 q-groups (lanes r, r+16, r+32, r+48)
#pragma unroll
    for (int sub = 0; sub < 4; ++sub) {
        hp[sub] = fminf(hp[sub], __shfl_xor(hp[sub], 16, 64));
        hp[sub] = fminf(hp[sub], __shfl_xor(hp[sub], 32, 64));
        hn[sub] = fmaxf(hn[sub], __shfl_xor(hn[sub], 16, 64));
        hn[sub] = fmaxf(hn[sub], __shfl_xor(hn[sub], 32, 64));
    }
    if (lane < 16) {
        const int pbase = blockIdx.y * NROWS;
#pragma unroll
        for (int sub = 0; sub < 4; ++sub) {
            int irow = ibase + sub * 16 + lane;
            hpp[pbase + irow] = hp[sub];
            hnp[pbase + irow] = hn[sub];
        }
    }
}

__global__ __launch_bounds__(256) void reduce_kernel(
    const float* __restrict__ hpp, const float* __restrict__ hnp,
    const float* __restrict__ sq, const int* __restrict__ labels,
    const int* __restrict__ hist, float* __restrict__ gsum,
    float* __restrict__ gcnt) {
    int row = blockIdx.x * 256 + threadIdx.x;
    float mnp = INFINITY, mxn = -INFINITY;
#pragma unroll 8
    for (int p = 0; p < JSPLIT; ++p) {
        mnp = fminf(mnp, hpp[p * NROWS + row]);
        mxn = fmaxf(mxn, hnp[p * NROWS + row]);
    }
    float s = sq[row];
    int h = hist[labels[row]];
    float sum = 0.f, cnt = 0.f;
    if (h >= 2 && h < NROWS) {
        float dp = sqrtf(fmaxf(s - 2.f * mnp, 1e-12f));
        float dn = sqrtf(fmaxf(s - 2.f * mxn, 1e-12f));
        sum = fmaxf(dp - dn + 0.3f, 1e-6f);
        cnt = 1.f;
    }
#pragma unroll
    for (int sh = 1; sh < 64; sh <<= 1) {
        sum += __shfl_xor(sum, sh, 64);
        cnt += __shfl_xor(cnt, sh, 64);
    }
    __shared__ float ss[4], sc[4];
    int w = threadIdx.x >> 6;
    if ((threadIdx.x & 63) == 0) { ss[w] = sum; sc[w] = cnt; }
    __syncthreads();
    if (threadIdx.x == 0) {
        atomicAdd(gsum, ss[0] + ss[1] + ss[2] + ss[3]);
        atomicAdd(gcnt, sc[0] + sc[1] + sc[2] + sc[3]);
    }
}

__global__ void final_kernel(const float* __restrict__ gsum,
                             const float* __restrict__ gcnt,
                             float* __restrict__ out) {
    out[0] = (gcnt[0] > 0.f) ? gsum[0] / gcnt[0] : 0.f;
}

extern "C" void kernel_launch(void* const* d_in, const int* in_sizes, int n_in,
                              void* d_out, int out_size, void* d_ws, size_t ws_size,
                              hipStream_t stream) {
    const float* x = (const float*)d_in[0];
    const int* labels = (const int*)d_in[1];
    float* out = (float*)d_out;

    // ws layout (16B-aligned):
    //   hist @ 0        (2 KB)  \ both zeroed by one 4 KB memset
    //   gsum @ 2048, gcnt @ 2052 /
    //   sq   @ 4096     (32 KB)
    //   hpp  @ 36864    (1 MB)   [JSPLIT x NROWS], every slot written by pair
    //   hnp  @ 1085440  (1 MB)
    //   xb   @ 2134016  (2 MB bf16)        total ~4.2 MB
    char* ws = (char*)d_ws;
    int* hist = (int*)ws;
    float* gsum = (float*)(ws + 2048);
    float* gcnt = (float*)(ws + 2052);
    float* sq = (float*)(ws + 4096);
    float* hpp = (float*)(ws + 36864);
    float* hnp = (float*)(ws + 1085440);
    unsigned short* xb = (unsigned short*)(ws + 2134016);

    hipMemsetAsync(ws, 0, 4096, stream);
    prep_kernel<<<(NROWS * 32) / 256, 256, 0, stream>>>(x, labels, sq, hist, xb);
    pair_kernel<<<dim3(NROWS / 256, JSPLIT), 256, 0, stream>>>(xb, sq, labels, hpp, hnp);
    reduce_kernel<<<NROWS / 256, 256, 0, stream>>>(hpp, hnp, sq, labels, hist, gsum, gcnt);
    final_kernel<<<1, 1, 0, stream>>>(gsum, gcnt, out);
}